// Round 1
// baseline (385.337 us; speedup 1.0000x reference)
//
#include <hip/hip_runtime.h>
#include <hip/hip_bf16.h>

// Problem constants
// x: (32, 256, 64, 64)  query: (32,256)  Wkv: (1024,256)  bkv: (1024)
// Wq: (512,256)  bq: (512)  Wfc: (256,512)  bfc: (256)
// B=32, C=256, T=4096, N_HEAD=8, D_HEAD=64, scale = 1/8

#define B_     32
#define C_     256
#define T_     4096
#define NH_    8
#define DH_    64

// ---------------------------------------------------------------------------
// K1: q = query @ Wq.T + bq  ->  qW[b,c,n] = scale * sum_d q[b,n,d] Wkv[n*64+d, c]
//     qb[b,n] = scale * sum_d q[b,n,d] * bkv[n*64+d]
// grid (NH_, B_), block 64 (one thread per d)
// ---------------------------------------------------------------------------
__global__ __launch_bounds__(64) void k_prep(
    const float* __restrict__ query, const float* __restrict__ Wkv,
    const float* __restrict__ bkv, const float* __restrict__ Wq,
    const float* __restrict__ bq, float* __restrict__ qWt,
    float* __restrict__ qb) {
  const int n = blockIdx.x;
  const int b = blockIdx.y;
  const int d = threadIdx.x;  // 0..63
  __shared__ float qs[64];

  const float* qrow = query + (size_t)b * C_;          // uniform -> scalar cache
  const float* wrow = Wq + (size_t)(n * DH_ + d) * C_; // per-thread row
  float s = bq[n * DH_ + d];
  #pragma unroll 4
  for (int c = 0; c < C_; c += 4) {
    float4 w = *(const float4*)(wrow + c);
    s += w.x * qrow[c] + w.y * qrow[c + 1] + w.z * qrow[c + 2] + w.w * qrow[c + 3];
  }
  qs[d] = s;
  __syncthreads();

  const float scale = 0.125f;  // 1/sqrt(64)
  if (d == 0) {
    float sb = 0.f;
    for (int dd = 0; dd < DH_; ++dd) sb += qs[dd] * bkv[n * DH_ + dd];
    qb[b * NH_ + n] = sb * scale;
  }
  // qW: thread covers c = d, d+64, d+128, d+192 (coalesced over d per dd)
  #pragma unroll
  for (int r = 0; r < 4; ++r) {
    const int c = d + r * 64;
    float acc = 0.f;
    for (int dd = 0; dd < DH_; ++dd)
      acc += qs[dd] * Wkv[(size_t)(n * DH_ + dd) * C_ + c];
    qWt[((size_t)b * C_ + c) * NH_ + n] = acc * scale;  // layout [b][c][n]
  }
}

// ---------------------------------------------------------------------------
// K2: logits[b,n,j] = qb[b,n] + sum_c qW[b,c,n] * x[b,c,j]   (already scaled)
// grid (16, B_), block 256: thread handles one j; x reads coalesced;
// qW reads are wave-uniform -> s_load from scalar cache.
// ---------------------------------------------------------------------------
__global__ __launch_bounds__(256) void k_logits(
    const float* __restrict__ x, const float* __restrict__ qWt,
    const float* __restrict__ qbv, float* __restrict__ logits) {
  const int b = blockIdx.y;
  const int j = blockIdx.x * 256 + threadIdx.x;
  const float* xb = x + (size_t)b * C_ * T_ + j;
  const float* qw = qWt + (size_t)b * C_ * NH_;
  const float* qb = qbv + b * NH_;

  float acc[NH_];
  #pragma unroll
  for (int n = 0; n < NH_; ++n) acc[n] = qb[n];

  #pragma unroll 4
  for (int c = 0; c < C_; ++c) {
    const float xv = xb[(size_t)c * T_];
    const float* qwc = qw + c * NH_;  // uniform address -> SGPR loads
    #pragma unroll
    for (int n = 0; n < NH_; ++n) acc[n] += qwc[n] * xv;
  }

  float* lg = logits + (size_t)b * NH_ * T_ + j;
  #pragma unroll
  for (int n = 0; n < NH_; ++n) lg[(size_t)n * T_] = acc[n];
}

// ---------------------------------------------------------------------------
// K3: in-place softmax over j (4096) per row; grid 256 rows, block 256.
// ---------------------------------------------------------------------------
__global__ __launch_bounds__(256) void k_softmax(float* __restrict__ lg) {
  float* p = lg + (size_t)blockIdx.x * T_;
  const int t = threadIdx.x;
  float4 v[4];
  #pragma unroll
  for (int i = 0; i < 4; ++i) v[i] = *(const float4*)(p + t * 4 + i * 1024);

  float m = -3.4e38f;
  #pragma unroll
  for (int i = 0; i < 4; ++i)
    m = fmaxf(m, fmaxf(fmaxf(v[i].x, v[i].y), fmaxf(v[i].z, v[i].w)));
  #pragma unroll
  for (int o = 32; o >= 1; o >>= 1) m = fmaxf(m, __shfl_xor(m, o));
  __shared__ float sm[4];
  if ((t & 63) == 0) sm[t >> 6] = m;
  __syncthreads();
  m = fmaxf(fmaxf(sm[0], sm[1]), fmaxf(sm[2], sm[3]));

  float s = 0.f;
  #pragma unroll
  for (int i = 0; i < 4; ++i) {
    v[i].x = expf(v[i].x - m); v[i].y = expf(v[i].y - m);
    v[i].z = expf(v[i].z - m); v[i].w = expf(v[i].w - m);
    s += v[i].x + v[i].y + v[i].z + v[i].w;
  }
  #pragma unroll
  for (int o = 32; o >= 1; o >>= 1) s += __shfl_xor(s, o);
  __shared__ float ss[4];
  if ((t & 63) == 0) ss[t >> 6] = s;
  __syncthreads();
  s = ss[0] + ss[1] + ss[2] + ss[3];
  const float inv = 1.0f / s;

  #pragma unroll
  for (int i = 0; i < 4; ++i) {
    v[i].x *= inv; v[i].y *= inv; v[i].z *= inv; v[i].w *= inv;
    *(float4*)(p + t * 4 + i * 1024) = v[i];
  }
}

// ---------------------------------------------------------------------------
// K4a: partial xattn[b,n,c] = sum_{j in tile} attn[b,n,j] * x[b,c,j]
// grid (16, B_) -> 256 j per block; block 256 threads (thread owns channel c).
// x tile staged in LDS with stride-33 padding (2-way bank aliasing = free);
// attn read with uniform indices -> scalar loads (SGPR operand FMAs).
// Partials written to part[b][jt][n][c]; reduced in K5.
// ---------------------------------------------------------------------------
#define BJ_  256
#define BJS_ 32
#define XPITCH_ 33
__global__ __launch_bounds__(256) void k_xattn(
    const float* __restrict__ x, const float* __restrict__ attn,
    float* __restrict__ part) {
  const int jt = blockIdx.x;
  const int b  = blockIdx.y;
  const int j0 = jt * BJ_;
  const int t  = threadIdx.x;
  __shared__ float xs[C_ * XPITCH_];  // 33 KB

  float acc[NH_];
  #pragma unroll
  for (int n = 0; n < NH_; ++n) acc[n] = 0.f;

  const float* xb = x + (size_t)b * C_ * T_;
  const float* ab = attn + (size_t)b * NH_ * T_;

  const int cr = t >> 3;          // 0..31
  const int jc = (t & 7) * 4;     // 0,4,...,28

  for (int sIt = 0; sIt < BJ_ / BJS_; ++sIt) {
    const int js = j0 + sIt * BJS_;
    __syncthreads();  // protect xs from previous iteration's readers
    // stage 256c x 32j (coalesced float4 global reads)
    #pragma unroll
    for (int p = 0; p < 8; ++p) {
      const int c = cr + p * 32;
      float4 vv = *(const float4*)(xb + (size_t)c * T_ + js + jc);
      float* dst = &xs[c * XPITCH_ + jc];
      dst[0] = vv.x; dst[1] = vv.y; dst[2] = vv.z; dst[3] = vv.w;
    }
    __syncthreads();
    // compute: thread owns c = t
    const float* xr = &xs[t * XPITCH_];
    #pragma unroll
    for (int jj = 0; jj < BJS_; ++jj) {
      const float xv = xr[jj];
      const int j = js + jj;  // uniform
      #pragma unroll
      for (int n = 0; n < NH_; ++n)
        acc[n] += ab[(size_t)n * T_ + j] * xv;  // uniform attn -> SGPR
    }
  }

  float* pb = part + ((size_t)b * 16 + jt) * (NH_ * C_);
  #pragma unroll
  for (int n = 0; n < NH_; ++n) pb[n * C_ + t] = acc[n];
}

// ---------------------------------------------------------------------------
// K5: reduce partials -> xattn; outvec[o] = bkv_v[o] + Wkv_v[o,:]·xattn[n(o),:];
//     out[m] = relu(bfc[m] + Wfc[m,:]·outvec). grid B_, block 256.
// ---------------------------------------------------------------------------
__global__ __launch_bounds__(256) void k_finish(
    const float* __restrict__ part, const float* __restrict__ Wkv,
    const float* __restrict__ bkv, const float* __restrict__ Wfc,
    const float* __restrict__ bfc, float* __restrict__ out) {
  __shared__ float xattn[NH_ * C_];  // 8 KB
  __shared__ float outv[512];
  const int b = blockIdx.x;
  const int t = threadIdx.x;

  const float* pb = part + (size_t)b * 16 * (NH_ * C_);
  for (int idx = t; idx < NH_ * C_; idx += 256) {
    float s = 0.f;
    #pragma unroll
    for (int jt = 0; jt < 16; ++jt) s += pb[(size_t)jt * (NH_ * C_) + idx];
    xattn[idx] = s;
  }
  __syncthreads();

  #pragma unroll
  for (int r = 0; r < 2; ++r) {
    const int o = t + r * 256;            // 0..511
    const int n = o >> 6;
    const float* wrow = Wkv + (size_t)(512 + o) * C_;
    const float* xa = &xattn[n * C_];     // wave-uniform -> LDS broadcast
    float s = bkv[512 + o];
    #pragma unroll 4
    for (int c = 0; c < C_; c += 4) {
      float4 w = *(const float4*)(wrow + c);
      s += w.x * xa[c] + w.y * xa[c + 1] + w.z * xa[c + 2] + w.w * xa[c + 3];
    }
    outv[o] = s;
  }
  __syncthreads();

  {
    const int m = t;
    const float* wrow = Wfc + (size_t)m * 512;
    float s = bfc[m];
    #pragma unroll 4
    for (int o = 0; o < 512; o += 4) {
      float4 w = *(const float4*)(wrow + o);
      s += w.x * outv[o] + w.y * outv[o + 1] + w.z * outv[o + 2] + w.w * outv[o + 3];
    }
    out[(size_t)b * 256 + m] = fmaxf(s, 0.f);
  }
}

// ---------------------------------------------------------------------------
extern "C" void kernel_launch(void* const* d_in, const int* in_sizes, int n_in,
                              void* d_out, int out_size, void* d_ws, size_t ws_size,
                              hipStream_t stream) {
  const float* x     = (const float*)d_in[0];
  const float* query = (const float*)d_in[1];
  const float* Wkv   = (const float*)d_in[2];
  const float* bkv   = (const float*)d_in[3];
  const float* Wq    = (const float*)d_in[4];
  const float* bq    = (const float*)d_in[5];
  const float* Wfc   = (const float*)d_in[6];
  const float* bfc   = (const float*)d_in[7];
  float* out = (float*)d_out;
  float* ws  = (float*)d_ws;

  // workspace layout (floats)
  float* qWt    = ws;                 // 32*256*8      = 65536
  float* qb     = ws + 65536;         // 32*8          = 256
  float* logits = ws + 65792;         // 32*8*4096     = 1048576 (becomes attn)
  float* part   = ws + 1114368;       // 32*16*8*256   = 1048576
  // total 2,162,944 floats = 8.65 MB

  k_prep   <<<dim3(NH_, B_), 64,  0, stream>>>(query, Wkv, bkv, Wq, bq, qWt, qb);
  k_logits <<<dim3(16,  B_), 256, 0, stream>>>(x, qWt, qb, logits);
  k_softmax<<<B_ * NH_,      256, 0, stream>>>(logits);
  k_xattn  <<<dim3(16,  B_), 256, 0, stream>>>(x, logits, part);
  k_finish <<<B_,            256, 0, stream>>>(part, Wkv, bkv, Wfc, bfc, out);
}

// Round 2
// 297.219 us; speedup vs baseline: 1.2965x; 1.2965x over previous
//
#include <hip/hip_runtime.h>
#include <hip/hip_bf16.h>

// x: (32, 256, 64, 64)  query: (32,256)  Wkv: (1024,256)  bkv: (1024)
// Wq: (512,256)  bq: (512)  Wfc: (256,512)  bfc: (256)
// B=32, C=256, T=4096, N_HEAD=8, D_HEAD=64, scale = 1/8

#define B_     32
#define C_     256
#define T_     4096
#define NH_    8
#define DH_    64

// ---------------------------------------------------------------------------
// K1: fold q-projection into Wkv_k:
//   qW[b,c,n] = scale * sum_d q[b,n,d] * Wkv[n*64+d, c]
//   qb[b,n]   = scale * sum_d q[b,n,d] * bkv[n*64+d]
// grid (2, B_), block 256: block h covers heads 4h..4h+3 (256 q outputs).
// Phase2 gives each thread 4 independent coalesced load streams (MLP).
// ---------------------------------------------------------------------------
__global__ __launch_bounds__(256) void k_prep(
    const float* __restrict__ query, const float* __restrict__ Wkv,
    const float* __restrict__ bkv, const float* __restrict__ Wq,
    const float* __restrict__ bq, float* __restrict__ qWt,
    float* __restrict__ qb) {
  const int hb = blockIdx.x;        // 0..1 (head group of 4)
  const int b  = blockIdx.y;
  const int t  = threadIdx.x;       // 0..255
  __shared__ float qrow_s[C_];
  __shared__ float qsh[256];        // q[b, hb*256 + t]

  qrow_s[t] = query[(size_t)b * C_ + t];
  __syncthreads();

  // phase 1: q[b, o] for o = hb*256 + t   (row-per-thread dot, L2-resident Wq)
  {
    const int o = hb * 256 + t;
    const float* wrow = Wq + (size_t)o * C_;
    float s = bq[o];
    #pragma unroll 8
    for (int c = 0; c < C_; c += 4) {
      float4 w = *(const float4*)(wrow + c);
      s += w.x * qrow_s[c] + w.y * qrow_s[c + 1] + w.z * qrow_s[c + 2] + w.w * qrow_s[c + 3];
    }
    qsh[t] = s;
  }
  __syncthreads();

  const float scale = 0.125f;
  // phase 2: thread owns column c = t; 4 heads per block, coalesced Wkv reads
  {
    const int c = t;
    float acc[4] = {0.f, 0.f, 0.f, 0.f};
    #pragma unroll 2
    for (int dd = 0; dd < DH_; ++dd) {
      #pragma unroll
      for (int nl = 0; nl < 4; ++nl) {
        const int row = (hb * 4 + nl) * DH_ + dd;
        acc[nl] += qsh[nl * DH_ + dd] * Wkv[(size_t)row * C_ + c];
      }
    }
    #pragma unroll
    for (int nl = 0; nl < 4; ++nl)
      qWt[((size_t)b * C_ + c) * NH_ + hb * 4 + nl] = acc[nl] * scale;
  }
  // phase 3: qb for this block's 4 heads
  if (t < 4) {
    const int n = hb * 4 + t;
    float s = 0.f;
    #pragma unroll 8
    for (int dd = 0; dd < DH_; ++dd)
      s += qsh[t * DH_ + dd] * bkv[n * DH_ + dd];
    qb[b * NH_ + n] = s * scale;
  }
}

// ---------------------------------------------------------------------------
// K2: logits[b,n,j] = qb[b,n] + sum_c qW[b,c,n] * x[b,c,j]
// grid (8, B_), block 256, 2 j per thread (float2 = 512B/wave-instr).
// qW tile in LDS, read as broadcast ds_read_b128.
// ---------------------------------------------------------------------------
__global__ __launch_bounds__(256) void k_logits(
    const float* __restrict__ x, const float* __restrict__ qWt,
    const float* __restrict__ qbv, float* __restrict__ logits) {
  const int b = blockIdx.y;
  const int t = threadIdx.x;
  const int j = blockIdx.x * 512 + t * 2;
  __shared__ float qws[C_ * NH_];  // 8 KB, layout [c][n]

  #pragma unroll
  for (int r = 0; r < 8; ++r) qws[r * 256 + t] = qWt[(size_t)b * (C_ * NH_) + r * 256 + t];
  __syncthreads();

  const float* xb = x + (size_t)b * C_ * T_ + j;
  const float* qb = qbv + b * NH_;

  float acc0[NH_], acc1[NH_];
  #pragma unroll
  for (int n = 0; n < NH_; ++n) { acc0[n] = qb[n]; acc1[n] = qb[n]; }

  #pragma unroll 4
  for (int c = 0; c < C_; ++c) {
    const float2 xv = *(const float2*)(xb + (size_t)c * T_);
    const float4 w0 = *(const float4*)(qws + c * 8);
    const float4 w1 = *(const float4*)(qws + c * 8 + 4);
    acc0[0] += w0.x * xv.x; acc1[0] += w0.x * xv.y;
    acc0[1] += w0.y * xv.x; acc1[1] += w0.y * xv.y;
    acc0[2] += w0.z * xv.x; acc1[2] += w0.z * xv.y;
    acc0[3] += w0.w * xv.x; acc1[3] += w0.w * xv.y;
    acc0[4] += w1.x * xv.x; acc1[4] += w1.x * xv.y;
    acc0[5] += w1.y * xv.x; acc1[5] += w1.y * xv.y;
    acc0[6] += w1.z * xv.x; acc1[6] += w1.z * xv.y;
    acc0[7] += w1.w * xv.x; acc1[7] += w1.w * xv.y;
  }

  float* lg = logits + (size_t)b * NH_ * T_ + j;
  #pragma unroll
  for (int n = 0; n < NH_; ++n) {
    float2 o; o.x = acc0[n]; o.y = acc1[n];
    *(float2*)(lg + (size_t)n * T_) = o;
  }
}

// ---------------------------------------------------------------------------
// K3: in-place softmax over j (4096) per (b,n) row; grid 256, block 256.
// ---------------------------------------------------------------------------
__global__ __launch_bounds__(256) void k_softmax(float* __restrict__ lg) {
  float* p = lg + (size_t)blockIdx.x * T_;
  const int t = threadIdx.x;
  float4 v[4];
  #pragma unroll
  for (int i = 0; i < 4; ++i) v[i] = *(const float4*)(p + t * 4 + i * 1024);

  float m = -3.4e38f;
  #pragma unroll
  for (int i = 0; i < 4; ++i)
    m = fmaxf(m, fmaxf(fmaxf(v[i].x, v[i].y), fmaxf(v[i].z, v[i].w)));
  #pragma unroll
  for (int o = 32; o >= 1; o >>= 1) m = fmaxf(m, __shfl_xor(m, o));
  __shared__ float sm[4];
  if ((t & 63) == 0) sm[t >> 6] = m;
  __syncthreads();
  m = fmaxf(fmaxf(sm[0], sm[1]), fmaxf(sm[2], sm[3]));

  float s = 0.f;
  #pragma unroll
  for (int i = 0; i < 4; ++i) {
    v[i].x = expf(v[i].x - m); v[i].y = expf(v[i].y - m);
    v[i].z = expf(v[i].z - m); v[i].w = expf(v[i].w - m);
    s += v[i].x + v[i].y + v[i].z + v[i].w;
  }
  #pragma unroll
  for (int o = 32; o >= 1; o >>= 1) s += __shfl_xor(s, o);
  __shared__ float ss[4];
  if ((t & 63) == 0) ss[t >> 6] = s;
  __syncthreads();
  s = ss[0] + ss[1] + ss[2] + ss[3];
  const float inv = 1.0f / s;

  #pragma unroll
  for (int i = 0; i < 4; ++i) {
    v[i].x *= inv; v[i].y *= inv; v[i].z *= inv; v[i].w *= inv;
    *(float4*)(p + t * 4 + i * 1024) = v[i];
  }
}

// ---------------------------------------------------------------------------
// K4: partial xattn[b,n,c] = sum_{j in tile} attn[b,n,j] * x[b,c,j]
// grid (16, B_), block 256. attn tile (256j x 8n, pitch 8) staged in LDS ONCE
// per block; x staged 32-j at a time (pitch 33: 2-way = free). Compute per j:
// 1 ds_read_b32 + 2 broadcast ds_read_b128 + 8 FMA.
// ---------------------------------------------------------------------------
#define BJ_  256
#define BJS_ 32
#define XPITCH_ 33
__global__ __launch_bounds__(256) void k_xattn(
    const float* __restrict__ x, const float* __restrict__ attn,
    float* __restrict__ part) {
  const int jt = blockIdx.x;
  const int b  = blockIdx.y;
  const int j0 = jt * BJ_;
  const int t  = threadIdx.x;
  __shared__ float xs[C_ * XPITCH_];   // 33 KB
  __shared__ float at[BJ_ * NH_];      // 8 KB, [local_j][n]

  const float* xb = x + (size_t)b * C_ * T_;
  const float* ab = attn + (size_t)b * NH_ * T_;

  // stage attn tile, transposed to [j][n] (coalesced global reads)
  #pragma unroll
  for (int n = 0; n < NH_; ++n) at[t * NH_ + n] = ab[(size_t)n * T_ + j0 + t];

  float acc[NH_];
  #pragma unroll
  for (int n = 0; n < NH_; ++n) acc[n] = 0.f;

  const int cr = t >> 3;          // 0..31
  const int jc = (t & 7) * 4;     // 0,4,...,28

  for (int sIt = 0; sIt < BJ_ / BJS_; ++sIt) {
    const int js = j0 + sIt * BJS_;
    __syncthreads();  // protect xs (and cover initial at staging)
    #pragma unroll
    for (int p = 0; p < 8; ++p) {
      const int c = cr + p * 32;
      float4 vv = *(const float4*)(xb + (size_t)c * T_ + js + jc);
      float* dst = &xs[c * XPITCH_ + jc];
      dst[0] = vv.x; dst[1] = vv.y; dst[2] = vv.z; dst[3] = vv.w;
    }
    __syncthreads();
    const float* xr = &xs[t * XPITCH_];
    const float* ar = &at[sIt * BJS_ * NH_];
    #pragma unroll 4
    for (int jj = 0; jj < BJS_; ++jj) {
      const float xv = xr[jj];
      const float4 w0 = *(const float4*)(ar + jj * 8);
      const float4 w1 = *(const float4*)(ar + jj * 8 + 4);
      acc[0] += w0.x * xv; acc[1] += w0.y * xv;
      acc[2] += w0.z * xv; acc[3] += w0.w * xv;
      acc[4] += w1.x * xv; acc[5] += w1.y * xv;
      acc[6] += w1.z * xv; acc[7] += w1.w * xv;
    }
  }

  float* pb = part + ((size_t)b * 16 + jt) * (NH_ * C_);
  #pragma unroll
  for (int n = 0; n < NH_; ++n) pb[n * C_ + t] = acc[n];
}

// ---------------------------------------------------------------------------
// K5: reduce partials -> xattn; outv[o] = bkv_v[o] + Wkv_v[o,:]·xattn[n(o),:];
//     out[m] = relu(bfc[m] + Wfc[m,:]·outv). grid B_, block 512.
// ---------------------------------------------------------------------------
__global__ __launch_bounds__(512) void k_finish(
    const float* __restrict__ part, const float* __restrict__ Wkv,
    const float* __restrict__ bkv, const float* __restrict__ Wfc,
    const float* __restrict__ bfc, float* __restrict__ out) {
  __shared__ float xattn[NH_ * C_];  // 8 KB
  __shared__ float outv[512];
  const int b = blockIdx.x;
  const int t = threadIdx.x;

  const float* pb = part + (size_t)b * 16 * (NH_ * C_);
  for (int idx = t; idx < NH_ * C_; idx += 512) {
    float s = 0.f;
    #pragma unroll
    for (int jt = 0; jt < 16; ++jt) s += pb[(size_t)jt * (NH_ * C_) + idx];
    xattn[idx] = s;
  }
  __syncthreads();

  {
    const int o = t;                      // 0..511
    const int n = o >> 6;
    const float* wrow = Wkv + (size_t)(512 + o) * C_;
    const float* xa = &xattn[n * C_];     // wave-uniform -> LDS broadcast
    float s = bkv[512 + o];
    #pragma unroll 8
    for (int c = 0; c < C_; c += 4) {
      float4 w = *(const float4*)(wrow + c);
      s += w.x * xa[c] + w.y * xa[c + 1] + w.z * xa[c + 2] + w.w * xa[c + 3];
    }
    outv[o] = s;
  }
  __syncthreads();

  if (t < 256) {
    const int m = t;
    const float* wrow = Wfc + (size_t)m * 512;
    float s = bfc[m];
    #pragma unroll 8
    for (int o = 0; o < 512; o += 4) {
      float4 w = *(const float4*)(wrow + o);
      s += w.x * outv[o] + w.y * outv[o + 1] + w.z * outv[o + 2] + w.w * outv[o + 3];
    }
    out[(size_t)b * 256 + m] = fmaxf(s, 0.f);
  }
}

// ---------------------------------------------------------------------------
extern "C" void kernel_launch(void* const* d_in, const int* in_sizes, int n_in,
                              void* d_out, int out_size, void* d_ws, size_t ws_size,
                              hipStream_t stream) {
  const float* x     = (const float*)d_in[0];
  const float* query = (const float*)d_in[1];
  const float* Wkv   = (const float*)d_in[2];
  const float* bkv   = (const float*)d_in[3];
  const float* Wq    = (const float*)d_in[4];
  const float* bq    = (const float*)d_in[5];
  const float* Wfc   = (const float*)d_in[6];
  const float* bfc   = (const float*)d_in[7];
  float* out = (float*)d_out;
  float* ws  = (float*)d_ws;

  // workspace layout (floats)
  float* qWt    = ws;                 // 32*256*8      = 65536
  float* qb     = ws + 65536;         // 32*8          = 256
  float* logits = ws + 65792;         // 32*8*4096     = 1048576 (becomes attn)
  float* part   = ws + 1114368;       // 32*16*8*256   = 1048576
  // total 2,162,944 floats = 8.65 MB

  k_prep   <<<dim3(2,  B_), 256, 0, stream>>>(query, Wkv, bkv, Wq, bq, qWt, qb);
  k_logits <<<dim3(8,  B_), 256, 0, stream>>>(x, qWt, qb, logits);
  k_softmax<<<B_ * NH_,     256, 0, stream>>>(logits);
  k_xattn  <<<dim3(16, B_), 256, 0, stream>>>(x, logits, part);
  k_finish <<<B_,           512, 0, stream>>>(part, Wkv, bkv, Wfc, bfc, out);
}

// Round 3
// 274.293 us; speedup vs baseline: 1.4048x; 1.0836x over previous
//
#include <hip/hip_runtime.h>
#include <hip/hip_bf16.h>

#define B_     32
#define C_     256
#define T_     4096
#define NH_    8
#define DH_    64

__global__ __launch_bounds__(256) void k_prep(
    const float* __restrict__ query, const float* __restrict__ Wkv,
    const float* __restrict__ bkv, const float* __restrict__ Wq,
    const float* __restrict__ bq, float* __restrict__ qWt,
    float* __restrict__ qb) {
  const int n = blockIdx.x;
  const int b = blockIdx.y;
  const int t = threadIdx.x;
  __shared__ float qrow_s[C_];
  __shared__ float psum[4 * 64];
  __shared__ float qsh[64];
  __shared__ float pb_s[64];

  qrow_s[t] = query[(size_t)b * C_ + t];
  __syncthreads();

  {
    const int d = t & 63, ch = t >> 6;
    const float* wrow = Wq + (size_t)(n * DH_ + d) * C_ + ch * 64;
    const float* qr = qrow_s + ch * 64;
    float s = 0.f;
    #pragma unroll
    for (int c = 0; c < 64; c += 4) {
      float4 w = *(const float4*)(wrow + c);
      s += w.x * qr[c] + w.y * qr[c + 1] + w.z * qr[c + 2] + w.w * qr[c + 3];
    }
    psum[ch * 64 + d] = s;
  }
  __syncthreads();
  if (t < 64)
    qsh[t] = bq[n * DH_ + t] + psum[t] + psum[64 + t] + psum[128 + t] + psum[192 + t];
  __syncthreads();

  const float scale = 0.125f;
  {
    const float* wk = Wkv + (size_t)(n * DH_) * C_ + t;
    float acc = 0.f;
    #pragma unroll 8
    for (int dd = 0; dd < DH_; ++dd) acc += qsh[dd] * wk[(size_t)dd * C_];
    qWt[((size_t)b * C_ + t) * NH_ + n] = acc * scale;
  }
  if (t < 64) pb_s[t] = qsh[t] * bkv[n * DH_ + t];
  __syncthreads();
  if (t == 0) {
    float s = 0.f;
    #pragma unroll 8
    for (int dd = 0; dd < 64; ++dd) s += pb_s[dd];
    qb[b * NH_ + n] = s * scale;
  }
}

__global__ __launch_bounds__(256) void k_logits(
    const float* __restrict__ x, const float* __restrict__ qWt,
    const float* __restrict__ qbv, float* __restrict__ lgpart) {
  const int half = blockIdx.y;
  const int b = blockIdx.z;
  const int t = threadIdx.x;
  const int j = blockIdx.x * 512 + t * 2;
  __shared__ float qws[128 * NH_];

  {
    const float4 v = *(const float4*)(qWt + (size_t)b * (C_ * NH_) + half * 1024 + t * 4);
    *(float4*)(qws + t * 4) = v;
  }
  __syncthreads();

  const float* xb = x + (size_t)b * C_ * T_ + (size_t)(half * 128) * T_ + j;
  const float* qb = qbv + b * NH_;

  float acc0[NH_], acc1[NH_];
  #pragma unroll
  for (int n = 0; n < NH_; ++n) {
    const float init = half ? 0.f : qb[n];
    acc0[n] = init; acc1[n] = init;
  }

  for (int c0 = 0; c0 < 128; c0 += 8) {
    float2 xv[8];
    #pragma unroll
    for (int cc = 0; cc < 8; ++cc)
      xv[cc] = *(const float2*)(xb + (size_t)(c0 + cc) * T_);
    #pragma unroll
    for (int cc = 0; cc < 8; ++cc) {
      const float4 w0 = *(const float4*)(qws + (c0 + cc) * 8);
      const float4 w1 = *(const float4*)(qws + (c0 + cc) * 8 + 4);
      acc0[0] += w0.x * xv[cc].x; acc1[0] += w0.x * xv[cc].y;
      acc0[1] += w0.y * xv[cc].x; acc1[1] += w0.y * xv[cc].y;
      acc0[2] += w0.z * xv[cc].x; acc1[2] += w0.z * xv[cc].y;
      acc0[3] += w0.w * xv[cc].x; acc1[3] += w0.w * xv[cc].y;
      acc0[4] += w1.x * xv[cc].x; acc1[4] += w1.x * xv[cc].y;
      acc0[5] += w1.y * xv[cc].x; acc1[5] += w1.y * xv[cc].y;
      acc0[6] += w1.z * xv[cc].x; acc1[6] += w1.z * xv[cc].y;
      acc0[7] += w1.w * xv[cc].x; acc1[7] += w1.w * xv[cc].y;
    }
  }

  float* lg = lgpart + (((size_t)half * B_ + b) * NH_) * T_ + j;
  #pragma unroll
  for (int n = 0; n < NH_; ++n) {
    float2 o; o.x = acc0[n]; o.y = acc1[n];
    *(float2*)(lg + (size_t)n * T_) = o;
  }
}

__global__ __launch_bounds__(256) void k_softmax(
    const float* __restrict__ lgpart, float* __restrict__ attn) {
  const size_t row = blockIdx.x;
  const float* p0 = lgpart + row * T_;
  const float* p1 = lgpart + ((size_t)B_ * NH_ + row) * T_;
  float* pa = attn + row * T_;
  const int t = threadIdx.x;
  float4 v[4];
  #pragma unroll
  for (int i = 0; i < 4; ++i) {
    float4 a = *(const float4*)(p0 + t * 4 + i * 1024);
    float4 c = *(const float4*)(p1 + t * 4 + i * 1024);
    v[i].x = a.x + c.x; v[i].y = a.y + c.y; v[i].z = a.z + c.z; v[i].w = a.w + c.w;
  }

  float m = -3.4e38f;
  #pragma unroll
  for (int i = 0; i < 4; ++i)
    m = fmaxf(m, fmaxf(fmaxf(v[i].x, v[i].y), fmaxf(v[i].z, v[i].w)));
  #pragma unroll
  for (int o = 32; o >= 1; o >>= 1) m = fmaxf(m, __shfl_xor(m, o));
  __shared__ float sm[4];
  if ((t & 63) == 0) sm[t >> 6] = m;
  __syncthreads();
  m = fmaxf(fmaxf(sm[0], sm[1]), fmaxf(sm[2], sm[3]));

  float s = 0.f;
  #pragma unroll
  for (int i = 0; i < 4; ++i) {
    v[i].x = expf(v[i].x - m); v[i].y = expf(v[i].y - m);
    v[i].z = expf(v[i].z - m); v[i].w = expf(v[i].w - m);
    s += v[i].x + v[i].y + v[i].z + v[i].w;
  }
  #pragma unroll
  for (int o = 32; o >= 1; o >>= 1) s += __shfl_xor(s, o);
  __shared__ float ss[4];
  if ((t & 63) == 0) ss[t >> 6] = s;
  __syncthreads();
  s = ss[0] + ss[1] + ss[2] + ss[3];
  const float inv = 1.0f / s;

  #pragma unroll
  for (int i = 0; i < 4; ++i) {
    v[i].x *= inv; v[i].y *= inv; v[i].z *= inv; v[i].w *= inv;
    *(float4*)(pa + t * 4 + i * 1024) = v[i];
  }
}

#define BJ_  256
#define BJS_ 32
#define XPITCH_ 33
__global__ __launch_bounds__(256) void k_xattn(
    const float* __restrict__ x, const float* __restrict__ attn,
    float* __restrict__ part) {
  const int jt = blockIdx.x;
  const int b  = blockIdx.y;
  const int j0 = jt * BJ_;
  const int t  = threadIdx.x;
  __shared__ float xs[C_ * XPITCH_];

  const float* xb = x + (size_t)b * C_ * T_;
  const float* ab = attn + (size_t)b * NH_ * T_ + j0;  // uniform base

  float acc[NH_];
  #pragma unroll
  for (int n = 0; n < NH_; ++n) acc[n] = 0.f;

  const int cr = t >> 3;
  const int jc = (t & 7) * 4;

  for (int sIt = 0; sIt < BJ_ / BJS_; ++sIt) {
    const int js = sIt * BJS_;
    __syncthreads();
    #pragma unroll
    for (int p = 0; p < 8; ++p) {
      const int c = cr + p * 32;
      float4 vv = *(const float4*)(xb + (size_t)c * T_ + j0 + js + jc);
      float* dst = &xs[c * XPITCH_ + jc];
      dst[0] = vv.x; dst[1] = vv.y; dst[2] = vv.z; dst[3] = vv.w;
    }
    __syncthreads();
    const float* xr = &xs[t * XPITCH_];
    #pragma unroll 4
    for (int jj = 0; jj < BJS_; ++jj) {
      const float xv = xr[jj];
      const int j = js + jj;  // wave-uniform
      #pragma unroll
      for (int n = 0; n < NH_; ++n)
        acc[n] += ab[(size_t)n * T_ + j] * xv;  // uniform -> scalar broadcast
    }
  }

  float* pb = part + ((size_t)b * 16 + jt) * (NH_ * C_);
  #pragma unroll
  for (int n = 0; n < NH_; ++n) pb[n * C_ + t] = acc[n];
}

// grid (2, B_): block hb computes v-rows o = hb*256 + t (256 rows),
// needing heads n = o>>6 = hb*4 .. hb*4+3.
__global__ __launch_bounds__(256) void k_outv(
    const float* __restrict__ part, const float* __restrict__ Wkv,
    const float* __restrict__ bkv, float* __restrict__ outvG) {
  __shared__ float xa_s[4 * C_];
  const int hb = blockIdx.x;
  const int b  = blockIdx.y;
  const int t  = threadIdx.x;

  const float* pb = part + (size_t)b * 16 * (NH_ * C_) + hb * (4 * C_);
  #pragma unroll
  for (int r = 0; r < 4; ++r) {
    const int idx = r * 256 + t;
    float s = 0.f;
    #pragma unroll
    for (int jt = 0; jt < 16; ++jt) s += pb[(size_t)jt * (NH_ * C_) + idx];
    xa_s[idx] = s;
  }
  __syncthreads();

  const int o = hb * 256 + t;                 // 0..511
  const float* wrow = Wkv + (size_t)(512 + o) * C_;
  const float* xa = &xa_s[(t >> 6) * C_];     // local head = (o>>6) - hb*4 = t>>6
  float s = bkv[512 + o];
  #pragma unroll 8
  for (int c = 0; c < C_; c += 4) {
    float4 w = *(const float4*)(wrow + c);
    s += w.x * xa[c] + w.y * xa[c + 1] + w.z * xa[c + 2] + w.w * xa[c + 3];
  }
  outvG[(size_t)b * 512 + o] = s;
}

__global__ __launch_bounds__(256) void k_fc(
    const float* __restrict__ outvG, const float* __restrict__ Wfc,
    const float* __restrict__ bfc, float* __restrict__ out) {
  __shared__ float ov[512];
  const int b = blockIdx.x;
  const int t = threadIdx.x;
  ov[t] = outvG[(size_t)b * 512 + t];
  ov[256 + t] = outvG[(size_t)b * 512 + 256 + t];
  __syncthreads();

  const float* wrow = Wfc + (size_t)t * 512;
  float s = bfc[t];
  #pragma unroll 8
  for (int o = 0; o < 512; o += 4) {
    float4 w = *(const float4*)(wrow + o);
    s += w.x * ov[o] + w.y * ov[o + 1] + w.z * ov[o + 2] + w.w * ov[o + 3];
  }
  out[(size_t)b * 256 + t] = fmaxf(s, 0.f);
}

extern "C" void kernel_launch(void* const* d_in, const int* in_sizes, int n_in,
                              void* d_out, int out_size, void* d_ws, size_t ws_size,
                              hipStream_t stream) {
  const float* x     = (const float*)d_in[0];
  const float* query = (const float*)d_in[1];
  const float* Wkv   = (const float*)d_in[2];
  const float* bkv   = (const float*)d_in[3];
  const float* Wq    = (const float*)d_in[4];
  const float* bq    = (const float*)d_in[5];
  const float* Wfc   = (const float*)d_in[6];
  const float* bfc   = (const float*)d_in[7];
  float* out = (float*)d_out;
  float* ws  = (float*)d_ws;

  float* qWt    = ws;                  // 65536
  float* qb     = ws + 65536;          // 256 (pad to 512)
  float* lgpart = ws + 66048;          // 2097152
  float* attn   = ws + 2163200;        // 1048576
  float* part   = ws + 3211776;        // 1048576
  float* outvG  = ws + 4260352;        // 16384

  k_prep   <<<dim3(NH_, B_),   256, 0, stream>>>(query, Wkv, bkv, Wq, bq, qWt, qb);
  k_logits <<<dim3(8, 2, B_),  256, 0, stream>>>(x, qWt, qb, lgpart);
  k_softmax<<<B_ * NH_,        256, 0, stream>>>(lgpart, attn);
  k_xattn  <<<dim3(16, B_),    256, 0, stream>>>(x, attn, part);
  k_outv   <<<dim3(2, B_),     256, 0, stream>>>(part, Wkv, bkv, outvG);
  k_fc     <<<B_,              256, 0, stream>>>(outvG, Wfc, bfc, out);
}